// Round 1
// baseline (1427.945 us; speedup 1.0000x reference)
//
#include <hip/hip_runtime.h>

typedef __bf16 bf16x8 __attribute__((ext_vector_type(8)));
typedef float  f32x4  __attribute__((ext_vector_type(4)));

#define BATCH_ 32768
#define VOC 4094

__device__ inline unsigned short f2bf(float f) {
    unsigned int u = __builtin_bit_cast(unsigned int, f);
    unsigned int r = u + 0x7FFFu + ((u >> 16) & 1u);
    return (unsigned short)(r >> 16);
}

__device__ inline f32x4 mfma16(bf16x8 a, bf16x8 b, f32x4 c) {
    return __builtin_amdgcn_mfma_f32_16x16x32_bf16(a, b, c, 0, 0, 0);
}

// ---------------- K0: weight prep (f32 -> bf16, concat layouts) ----------------
// wg rows: [0,256)=r  [256,512)=z  -> [W_ih | W_hh]
//          [512,768)=i_n -> [W_ih | 0]
//          [768,1024)=h_n -> [0 | W_hh(rows 512..767)]
__global__ __launch_bounds__(256) void k_prep(
    const float* __restrict__ comb_W, const float* __restrict__ W_ih,
    const float* __restrict__ W_hh, const float* __restrict__ out_W,
    const float* __restrict__ b_ih, const float* __restrict__ b_hh,
    unsigned short* __restrict__ cwb, unsigned short* __restrict__ wg,
    unsigned short* __restrict__ owb, float* __restrict__ bg) {
    int i = blockIdx.x * 256 + threadIdx.x;      // grid covers 1,048,576
    if (i < 512 * 768) cwb[i] = f2bf(comb_W[i]);
    if (i < 1024 * 768) {
        int g = i / 768, k = i - g * 768;
        float v;
        if (k < 512) v = (g < 768) ? W_ih[g * 512 + k] : 0.f;
        else v = (g < 512) ? W_hh[g * 256 + (k - 512)]
                           : ((g >= 768) ? W_hh[(g - 256) * 256 + (k - 512)] : 0.f);
        wg[i] = f2bf(v);
    }
    if (i < 4096 * 256) {
        int r = i >> 8;
        owb[i] = (r < VOC) ? f2bf(out_W[i]) : (unsigned short)0;
    }
    if (i < 1024) {
        float v = (i < 512) ? (b_ih[i] + b_hh[i]) : ((i < 768) ? b_ih[i] : b_hh[i - 256]);
        bg[i] = v;
    }
}

// ---------------- K1: attention + embedding gather (wave per row) ----------------
__global__ __launch_bounds__(256) void k_attn(
    const int* __restrict__ dw, const float* __restrict__ hidden,
    const float* __restrict__ enc, const float* __restrict__ emb,
    const float* __restrict__ aW, const float* __restrict__ ab,
    unsigned short* __restrict__ xcat, unsigned short* __restrict__ xh) {
    __shared__ float sAW[9 * 516];
    __shared__ float sAB[9];
    int tid = threadIdx.x;
    for (int i = tid; i < 9 * 512; i += 256) {
        int m = i >> 9, k = i & 511;
        sAW[m * 516 + k] = aW[i];
    }
    if (tid < 9) sAB[tid] = ab[tid];
    __syncthreads();
    int w = tid >> 6, lane = tid & 63;
    int b = blockIdx.x * 4 + w;
    const float* encb = enc + (size_t)b * (9 * 256);
    float4 h4 = *(const float4*)(hidden + (size_t)b * 256 + 4 * lane);

    float u[9];
#pragma unroll
    for (int m = 0; m < 9; m++) {
        float4 a = *(const float4*)&sAW[m * 516 + 256 + 4 * lane];
        float v = h4.x * a.x + h4.y * a.y + h4.z * a.z + h4.w * a.w;
        v += __shfl_xor(v, 1);  v += __shfl_xor(v, 2);  v += __shfl_xor(v, 4);
        v += __shfl_xor(v, 8);  v += __shfl_xor(v, 16); v += __shfl_xor(v, 32);
        u[m] = v + sAB[m];
    }
    float wsum[9] = {0, 0, 0, 0, 0, 0, 0, 0, 0};
#pragma unroll
    for (int l = 0; l < 9; l++) {
        float4 e = *(const float4*)(encb + l * 256 + 4 * lane);
        float p[9];
#pragma unroll
        for (int m = 0; m < 9; m++) {
            float4 a = *(const float4*)&sAW[m * 516 + 4 * lane];
            float v = e.x * a.x + e.y * a.y + e.z * a.z + e.w * a.w;
            v += __shfl_xor(v, 1);  v += __shfl_xor(v, 2);  v += __shfl_xor(v, 4);
            v += __shfl_xor(v, 8);  v += __shfl_xor(v, 16); v += __shfl_xor(v, 32);
            p[m] = v + u[m];
        }
        float mx = p[0];
#pragma unroll
        for (int m = 1; m < 9; m++) mx = fmaxf(mx, p[m]);
        float s = 0.f, ex[9];
#pragma unroll
        for (int m = 0; m < 9; m++) { ex[m] = __expf(p[m] - mx); s += ex[m]; }
        float inv = 1.f / s;
#pragma unroll
        for (int m = 0; m < 9; m++) wsum[m] += ex[m] * inv;
    }
    float c0 = 0, c1 = 0, c2 = 0, c3 = 0;
#pragma unroll
    for (int m = 0; m < 9; m++) {
        float4 e = *(const float4*)(encb + m * 256 + 4 * lane);
        c0 += wsum[m] * e.x; c1 += wsum[m] * e.y;
        c2 += wsum[m] * e.z; c3 += wsum[m] * e.w;
    }
    ushort4 cb; cb.x = f2bf(c0); cb.y = f2bf(c1); cb.z = f2bf(c2); cb.w = f2bf(c3);
    *(ushort4*)(xcat + (size_t)b * 768 + 512 + 4 * lane) = cb;
    ushort4 hb; hb.x = f2bf(h4.x); hb.y = f2bf(h4.y); hb.z = f2bf(h4.z); hb.w = f2bf(h4.w);
    *(ushort4*)(xh + (size_t)b * 768 + 512 + 4 * lane) = hb;

    int word = dw[b];
    const float* er = emb + (size_t)word * 512 + 8 * lane;
    float4 e0 = *(const float4*)er;
    float4 e1 = *(const float4*)(er + 4);
    ushort4 w0; w0.x = f2bf(e0.x); w0.y = f2bf(e0.y); w0.z = f2bf(e0.z); w0.w = f2bf(e0.w);
    ushort4 w1; w1.x = f2bf(e1.x); w1.y = f2bf(e1.y); w1.z = f2bf(e1.z); w1.w = f2bf(e1.w);
    *(ushort4*)(xcat + (size_t)b * 768 + 8 * lane) = w0;
    *(ushort4*)(xcat + (size_t)b * 768 + 8 * lane + 4) = w1;
}

// ---------------- K2: x = relu(xcat @ comb_W^T + comb_b) -> xh[:,0:512] ----------------
__global__ __launch_bounds__(256) void k_combine(
    const unsigned short* __restrict__ xcat, const unsigned short* __restrict__ cwb,
    const float* __restrict__ comb_b, unsigned short* __restrict__ xh) {
    int tid = threadIdx.x, w = tid >> 6, lane = tid & 63;
    int lo = lane & 15, hi = lane >> 4;
    int bm0 = blockIdx.x * 128, bn0 = blockIdx.y * 64;
    int arow = bm0 + 32 * w + lo;
    const __bf16* A = (const __bf16*)xcat;
    const __bf16* Bw = (const __bf16*)cwb;
    f32x4 acc[2][4] = {};
    for (int ks = 0; ks < 24; ks++) {
        int k = ks * 32 + 8 * hi;
        bf16x8 a0 = *(const bf16x8*)(A + (size_t)arow * 768 + k);
        bf16x8 a1 = *(const bf16x8*)(A + (size_t)(arow + 16) * 768 + k);
#pragma unroll
        for (int nf = 0; nf < 4; nf++) {
            bf16x8 bfr = *(const bf16x8*)(Bw + (size_t)(bn0 + nf * 16 + lo) * 768 + k);
            acc[0][nf] = mfma16(a0, bfr, acc[0][nf]);
            acc[1][nf] = mfma16(a1, bfr, acc[1][nf]);
        }
    }
#pragma unroll
    for (int nf = 0; nf < 4; nf++) {
        int col = bn0 + nf * 16 + lo;
        float cb = comb_b[col];
#pragma unroll
        for (int mf = 0; mf < 2; mf++) {
            int rbase = bm0 + 32 * w + mf * 16 + hi * 4;
#pragma unroll
            for (int r = 0; r < 4; r++) {
                float v = fmaxf(acc[mf][nf][r] + cb, 0.f);
                xh[(size_t)(rbase + r) * 768 + col] = f2bf(v);
            }
        }
    }
}

// ---------------- K3: GRU gates GEMM + elementwise -> h_new ----------------
__global__ __launch_bounds__(256) void k_gru(
    const unsigned short* __restrict__ xh, const unsigned short* __restrict__ wg,
    const float* __restrict__ bg, const float* __restrict__ hidden,
    float* __restrict__ hnew_out, unsigned short* __restrict__ hnb) {
    __shared__ float S[128][65];
    int tid = threadIdx.x, w = tid >> 6, lane = tid & 63;
    int lo = lane & 15, hi = lane >> 4;
    int bm0 = blockIdx.x * 128;
    int h0 = blockIdx.y * 16;
    int arow = bm0 + 32 * w + lo;
    const __bf16* A = (const __bf16*)xh;
    const __bf16* Bw = (const __bf16*)wg;
    f32x4 acc[2][4] = {};
    for (int ks = 0; ks < 24; ks++) {
        int k = ks * 32 + 8 * hi;
        bf16x8 a0 = *(const bf16x8*)(A + (size_t)arow * 768 + k);
        bf16x8 a1 = *(const bf16x8*)(A + (size_t)(arow + 16) * 768 + k);
#pragma unroll
        for (int nf = 0; nf < 4; nf++) {
            bf16x8 bfr = *(const bf16x8*)(Bw + (size_t)(nf * 256 + h0 + lo) * 768 + k);
            acc[0][nf] = mfma16(a0, bfr, acc[0][nf]);
            acc[1][nf] = mfma16(a1, bfr, acc[1][nf]);
        }
    }
#pragma unroll
    for (int mf = 0; mf < 2; mf++)
#pragma unroll
        for (int nf = 0; nf < 4; nf++)
#pragma unroll
            for (int r = 0; r < 4; r++)
                S[32 * w + mf * 16 + hi * 4 + r][nf * 16 + lo] = acc[mf][nf][r];
    __syncthreads();
    for (int it = 0; it < 8; it++) {
        int idx = it * 256 + tid;          // 128 rows x 16 h
        int row = idx >> 4, h = idx & 15;
        int hg = h0 + h;
        float sr = S[row][h], sz = S[row][16 + h];
        float si = S[row][32 + h], sh = S[row][48 + h];
        float r = 1.f / (1.f + __expf(-(sr + bg[hg])));
        float z = 1.f / (1.f + __expf(-(sz + bg[256 + hg])));
        float n = tanhf(si + bg[512 + hg] + r * (sh + bg[768 + hg]));
        float hp = hidden[(size_t)(bm0 + row) * 256 + hg];
        float hn = z * (hp - n) + n;
        hnew_out[(size_t)(bm0 + row) * 256 + hg] = hn;
        hnb[(size_t)(bm0 + row) * 256 + hg] = f2bf(hn);
    }
}

// ---------------- K4a: lse[b] = log(sum_v exp(h_new @ out_W^T + out_b)) ----------------
__global__ __launch_bounds__(256) void k_lse(
    const unsigned short* __restrict__ hnb, const unsigned short* __restrict__ owb,
    const float* __restrict__ out_b, float* __restrict__ lse) {
    __shared__ float sums[2][64];
    int tid = threadIdx.x, w = tid >> 6, lane = tid & 63;
    int lo = lane & 15, hi = lane >> 4;
    int wr = w >> 1, wc = w & 1;
    int bm0 = blockIdx.x * 64;
    const __bf16* A = (const __bf16*)hnb;
    const __bf16* Bw = (const __bf16*)owb;
    bf16x8 Af[2][8];
#pragma unroll
    for (int mf = 0; mf < 2; mf++)
#pragma unroll
        for (int ks = 0; ks < 8; ks++)
            Af[mf][ks] = *(const bf16x8*)(A + (size_t)(bm0 + 32 * wr + mf * 16 + lo) * 256 + ks * 32 + 8 * hi);
    float se[2][4] = {};
    for (int c = wc; c < 128; c += 2) {
        int n0 = c * 32;
        f32x4 acc[2][2] = {};
#pragma unroll
        for (int ks = 0; ks < 8; ks++) {
            int k = ks * 32 + 8 * hi;
            bf16x8 b0 = *(const bf16x8*)(Bw + (size_t)(n0 + lo) * 256 + k);
            bf16x8 b1 = *(const bf16x8*)(Bw + (size_t)(n0 + 16 + lo) * 256 + k);
            acc[0][0] = mfma16(Af[0][ks], b0, acc[0][0]);
            acc[0][1] = mfma16(Af[0][ks], b1, acc[0][1]);
            acc[1][0] = mfma16(Af[1][ks], b0, acc[1][0]);
            acc[1][1] = mfma16(Af[1][ks], b1, acc[1][1]);
        }
#pragma unroll
        for (int nf = 0; nf < 2; nf++) {
            int col = n0 + nf * 16 + lo;
            bool ok = col < VOC;
            float ob = ok ? out_b[col] : 0.f;
#pragma unroll
            for (int mf = 0; mf < 2; mf++)
#pragma unroll
                for (int r = 0; r < 4; r++)
                    se[mf][r] += ok ? __expf(acc[mf][nf][r] + ob) : 0.f;
        }
    }
#pragma unroll
    for (int mf = 0; mf < 2; mf++)
#pragma unroll
        for (int r = 0; r < 4; r++) {
            float v = se[mf][r];
            v += __shfl_xor(v, 1); v += __shfl_xor(v, 2);
            v += __shfl_xor(v, 4); v += __shfl_xor(v, 8);
            se[mf][r] = v;
        }
    if (lo == 0) {
#pragma unroll
        for (int mf = 0; mf < 2; mf++)
#pragma unroll
            for (int r = 0; r < 4; r++)
                sums[wc][32 * wr + mf * 16 + hi * 4 + r] = se[mf][r];
    }
    __syncthreads();
    if (tid < 64) lse[bm0 + tid] = __logf(sums[0][tid] + sums[1][tid]);
}

// ---------------- K4b: out = logits - lse ----------------
__global__ __launch_bounds__(256) void k_out(
    const unsigned short* __restrict__ hnb, const unsigned short* __restrict__ owb,
    const float* __restrict__ out_b, const float* __restrict__ lse,
    float* __restrict__ out) {
    int tid = threadIdx.x, w = tid >> 6, lane = tid & 63;
    int lo = lane & 15, hi = lane >> 4;
    int wr = w >> 1, wc = w & 1;
    int bm0 = blockIdx.x * 64;
    int nbase = blockIdx.y * 1024;
    const __bf16* A = (const __bf16*)hnb;
    const __bf16* Bw = (const __bf16*)owb;
    bf16x8 Af[2][8];
#pragma unroll
    for (int mf = 0; mf < 2; mf++)
#pragma unroll
        for (int ks = 0; ks < 8; ks++)
            Af[mf][ks] = *(const bf16x8*)(A + (size_t)(bm0 + 32 * wr + mf * 16 + lo) * 256 + ks * 32 + 8 * hi);
    float ls[2][4];
#pragma unroll
    for (int mf = 0; mf < 2; mf++)
#pragma unroll
        for (int r = 0; r < 4; r++)
            ls[mf][r] = lse[bm0 + 32 * wr + mf * 16 + hi * 4 + r];
    for (int c = wc; c < 32; c += 2) {
        int n0 = nbase + c * 32;
        f32x4 acc[2][2] = {};
#pragma unroll
        for (int ks = 0; ks < 8; ks++) {
            int k = ks * 32 + 8 * hi;
            bf16x8 b0 = *(const bf16x8*)(Bw + (size_t)(n0 + lo) * 256 + k);
            bf16x8 b1 = *(const bf16x8*)(Bw + (size_t)(n0 + 16 + lo) * 256 + k);
            acc[0][0] = mfma16(Af[0][ks], b0, acc[0][0]);
            acc[0][1] = mfma16(Af[0][ks], b1, acc[0][1]);
            acc[1][0] = mfma16(Af[1][ks], b0, acc[1][0]);
            acc[1][1] = mfma16(Af[1][ks], b1, acc[1][1]);
        }
#pragma unroll
        for (int nf = 0; nf < 2; nf++) {
            int col = n0 + nf * 16 + lo;
            if (col < VOC) {
                float ob = out_b[col];
#pragma unroll
                for (int mf = 0; mf < 2; mf++) {
                    int rbase = bm0 + 32 * wr + mf * 16 + hi * 4;
#pragma unroll
                    for (int r = 0; r < 4; r++)
                        out[(size_t)(rbase + r) * VOC + col] = acc[mf][nf][r] + ob - ls[mf][r];
                }
            }
        }
    }
}

extern "C" void kernel_launch(void* const* d_in, const int* in_sizes, int n_in,
                              void* d_out, int out_size, void* d_ws, size_t ws_size,
                              hipStream_t stream) {
    const int*   dw      = (const int*)d_in[0];
    const float* hidden  = (const float*)d_in[1];
    const float* enc     = (const float*)d_in[2];
    const float* emb     = (const float*)d_in[3];
    const float* aW      = (const float*)d_in[4];
    const float* ab      = (const float*)d_in[5];
    const float* comb_W  = (const float*)d_in[6];
    const float* comb_b  = (const float*)d_in[7];
    const float* W_ih    = (const float*)d_in[8];
    const float* b_ih    = (const float*)d_in[9];
    const float* W_hh    = (const float*)d_in[10];
    const float* b_hh    = (const float*)d_in[11];
    const float* out_W   = (const float*)d_in[12];
    const float* out_b   = (const float*)d_in[13];

    float* out = (float*)d_out;
    float* hnew_out = out + (size_t)BATCH_ * VOC;

    unsigned short* xcat = (unsigned short*)d_ws;
    unsigned short* xh   = xcat + (size_t)BATCH_ * 768;
    unsigned short* hnb  = xh + (size_t)BATCH_ * 768;
    float* lse           = (float*)(hnb + (size_t)BATCH_ * 256);
    unsigned short* cwb  = (unsigned short*)(lse + BATCH_);
    unsigned short* wg   = cwb + 512 * 768;
    unsigned short* owb  = wg + 1024 * 768;
    float* bg            = (float*)(owb + 4096 * 256);

    k_prep<<<4096, 256, 0, stream>>>(comb_W, W_ih, W_hh, out_W, b_ih, b_hh, cwb, wg, owb, bg);
    k_attn<<<BATCH_ / 4, 256, 0, stream>>>(dw, hidden, enc, emb, aW, ab, xcat, xh);
    k_combine<<<dim3(BATCH_ / 128, 8), 256, 0, stream>>>(xcat, cwb, comb_b, xh);
    k_gru<<<dim3(BATCH_ / 128, 16), 256, 0, stream>>>(xh, wg, bg, hidden, hnew_out, hnb);
    k_lse<<<BATCH_ / 64, 256, 0, stream>>>(hnb, owb, out_b, lse);
    k_out<<<dim3(BATCH_ / 64, 4), 256, 0, stream>>>(hnb, owb, out_b, lse, out);
}